// Round 5
// baseline (260.247 us; speedup 1.0000x reference)
//
#include <hip/hip_runtime.h>

// LaBramChannelPatcher: [B=16, W=32, T=1000, C=64] fp32 ->
//   patches [B, W, 320, 200]  (== per-(b,w) transpose [T,C] -> [C,T])
//   channel_indices [320] = repeat(arange(64), 5)
//   time_indices    [320] = tile(arange(5), 64)
//
// Round 5: wave-private LDS transpose, ZERO barriers. Each wave owns a
// 20t x 64c slice; ordering is in-wave lgkmcnt only (DS ops are in-order
// per wave). 26 KB LDS/block -> 6 blocks/CU -> 30 waves (94%). Plain
// stores (not NT) so L2 write-combines the 80 B lane-runs into full lines.

#define TDIM 1000
#define CDIM 64
#define LSTR 65                 // LDS row stride in words (odd -> low conflicts)
#define WROWS 20                // t-rows per wave
#define WSLICE (WROWS * LSTR)   // 1300 words = 5200 B per wave slice
#define NTILE 10                // 100-t tiles per (b,w)
#define PATCH_ELEMS 32768000    // 16*32*320*200

typedef float v4f __attribute__((ext_vector_type(4)));

__global__ __launch_bounds__(320) void labram_patcher_kernel(
    const float* __restrict__ in, float* __restrict__ out)
{
    __shared__ float lds[5 * WSLICE];   // 26000 B, one slice per wave

    const int tid  = threadIdx.x;       // 0..319
    const int lane = tid & 63;
    const int w    = tid >> 6;          // wave id 0..4
    const int tile = blockIdx.x % NTILE;
    const int bw   = blockIdx.x / NTILE;        // 0..511
    const int t0   = tile * 100 + w * WROWS;    // this wave's first t-row

    float* slice = lds + w * WSLICE;

    // ---- Phase 1 (wave-local): 5 coalesced float4 loads (1 KB/wave/instr),
    //      scatter into slice[ti][c]. 20 rows x 16 float4 = 320 per wave. ----
    const v4f* in4 = (const v4f*)in + (size_t)(bw * TDIM + t0) * (CDIM / 4);
    v4f v[5];
#pragma unroll
    for (int k = 0; k < 5; ++k)
        v[k] = in4[lane + 64 * k];
#pragma unroll
    for (int k = 0; k < 5; ++k) {
        int idx = lane + 64 * k;       // 0..319
        int ti  = idx >> 4;            // 0..19
        int c4  = idx & 15;            // 0..15
        float* p = slice + ti * LSTR + c4 * 4;
        p[0] = v[k].x; p[1] = v[k].y; p[2] = v[k].z; p[3] = v[k].w;
    }

    // No __syncthreads: slice is wave-private; DS ops from one wave complete
    // in order (lgkmcnt). wave_barrier just pins compiler scheduling.
    __builtin_amdgcn_wave_barrier();

    // ---- Phase 2 (wave-local): gather 4 consecutive-t scalars per lane,
    //      5 coalesced float4 stores. 64 c x 5 j-groups = 320 per wave. ----
    v4f o[5];
    int cc[5], jj[5];
#pragma unroll
    for (int k = 0; k < 5; ++k) {
        int idx = lane + 64 * k;       // (c, j), j fastest
        int c   = idx / 5;
        int j   = idx - 5 * c;
        cc[k] = c; jj[k] = j;
        int b = (j * 4) * LSTR + c;
        o[k].x = slice[b];
        o[k].y = slice[b + LSTR];
        o[k].z = slice[b + 2 * LSTR];
        o[k].w = slice[b + 3 * LSTR];
    }
#pragma unroll
    for (int k = 0; k < 5; ++k) {
        size_t off = (size_t)(bw * CDIM + cc[k]) * TDIM + (t0 + jj[k] * 4);
        *(v4f*)(out + off) = o[k];
    }

    // ---- Index outputs (tiny): block 0, one entry per thread ----
    if (blockIdx.x == 0) {
        out[PATCH_ELEMS + tid]       = (float)(tid / 5);  // channel_indices
        out[PATCH_ELEMS + 320 + tid] = (float)(tid % 5);  // time_indices
    }
}

extern "C" void kernel_launch(void* const* d_in, const int* in_sizes, int n_in,
                              void* d_out, int out_size, void* d_ws, size_t ws_size,
                              hipStream_t stream) {
    const float* in = (const float*)d_in[0];
    float* out = (float*)d_out;
    // 512 (b,w) slices * 10 t-tiles, 5 waves/block each owning 20 t-rows
    dim3 grid(512 * NTILE);
    dim3 block(320);
    labram_patcher_kernel<<<grid, block, 0, stream>>>(in, out);
}